// Round 9
// baseline (205.627 us; speedup 1.0000x reference)
//
#include <hip/hip_runtime.h>
#include <hip/hip_bf16.h>

// Problem constants (B=2, T=2048, D=1024, H=16, hd=64)
#define T_SEQ 2048
#define DM    1024
#define MTOT  4096   // B*T

typedef short v8s __attribute__((ext_vector_type(8)));   // 8 x bf16 (4 VGPRs)
typedef short v4s __attribute__((ext_vector_type(4)));   // 4 x bf16 (2 VGPRs)
typedef float v4f __attribute__((ext_vector_type(4)));   // MFMA accumulator

// fast pack: two fp32 -> packed bf16x2 (round-half-up) via v_perm_b32
__device__ __forceinline__ unsigned int pk2(float a, float b) {
  unsigned int ua = __float_as_uint(a) + 0x8000u;
  unsigned int ub = __float_as_uint(b) + 0x8000u;
  return __builtin_amdgcn_perm(ub, ua, 0x07060302u);  // [ub_hi16, ua_hi16]
}

// two fp32 -> packed bf16x2 with round-to-nearest-EVEN (matches old f2bf)
__device__ __forceinline__ unsigned int rne2(float a, float b) {
  unsigned int ua = __float_as_uint(a);
  ua += ((ua >> 16) & 1u) + 0x7fffu;
  unsigned int ub = __float_as_uint(b);
  ub += ((ub >> 16) & 1u) + 0x7fffu;
  return __builtin_amdgcn_perm(ub, ua, 0x07060302u);
}

// 8 fp32 (two float4) -> 8 bf16 (RNE), ready for ds_write_b128
__device__ __forceinline__ v8s pack8f(float4 a, float4 b) {
  union { v8s s; unsigned int u[4]; } o;
  o.u[0] = rne2(a.x, a.y);
  o.u[1] = rne2(a.z, a.w);
  o.u[2] = rne2(b.x, b.y);
  o.u[3] = rne2(b.z, b.w);
  return o.s;
}

// pack two v4f (P^T C-layout regs) -> one v8s B-operand for K=32 PV mfma
__device__ __forceinline__ v8s pack8bf(v4f a, v4f b) {
  union { v8s s; unsigned int u[4]; } o;
  o.u[0] = pk2(a[0], a[1]);
  o.u[1] = pk2(a[2], a[3]);
  o.u[2] = pk2(b[0], b[1]);
  o.u[3] = pk2(b[2], b[3]);
  return o.s;
}

// raw v_exp_f32 (2^x); denormal output flushes to 0 which is what we want
__device__ __forceinline__ float fast_exp2(float x) {
#if __has_builtin(__builtin_amdgcn_exp2f)
  return __builtin_amdgcn_exp2f(x);
#else
  return exp2f(x);
#endif
}

// async global->LDS, 16B per lane: lane i lands at lds + i*16 (wave-uniform base).
__device__ __forceinline__ void gload16(const void* g, void* lds) {
  __builtin_amdgcn_global_load_lds(
      (const __attribute__((address_space(1))) unsigned int*)g,
      (__attribute__((address_space(3))) unsigned int*)lds, 16, 0, 0);
}

// ---------------------------------------------------------------------------
// FUSED QKV v5: convert-on-the-fly.  fused2's 128M x (3x64)N MFMA structure
// (48 MFMA/wave/K-step) but reads x/Wq/Wk/Wv as fp32 DIRECTLY: per K-step
// each thread loads 20 float4 to regs (issued BEFORE compute of the current
// chunk -> T14 split, HBM latency hides under MFMA), RNE-packs to bf16 in
// register, ds_write_b128 into the same swizzled LDS layout (we control
// both sides).  Double-buffered 2x40KB LDS, ONE barrier per K-step.
// This eliminates the convert_all kernel entirely (one dispatch + 42MB of
// bf16 round-trip traffic).  VGPR ~210 -> still 2 waves/SIMD = 2 blocks/CU
// (LDS-capped at 80KB anyway).  Grid (32,16)=512.
// ---------------------------------------------------------------------------
__global__ __launch_bounds__(256) void qkv_fused5(
    const float* __restrict__ x,
    const float* __restrict__ Wq, const float* __restrict__ Wk,
    const float* __restrict__ Wv,
    unsigned short* __restrict__ Qw, unsigned short* __restrict__ Kw,
    unsigned short* __restrict__ Vtw)
{
  __shared__ unsigned short smem[2][20480];   // 2 x 40KB: As[128][64] | 3x Wz[64][64]

  const int tid  = threadIdx.x;
  const int wv   = tid >> 6, l = tid & 63;
  const int lrow = l & 15, lq = l >> 4;
  const int wm = wv >> 1;        // m-half (64 rows)
  const int wn = wv & 1;         // n-half (32 cols)
  const int srow = l >> 3, sslot = l & 7;
  const int swz  = sslot ^ (srow & 7);
  const int m0 = blockIdx.x * 128, n0 = blockIdx.y * 64;

  v4f acc[3][4][2];
#pragma unroll
  for (int z = 0; z < 3; ++z)
#pragma unroll
    for (int mt = 0; mt < 4; ++mt)
#pragma unroll
      for (int nt = 0; nt < 2; ++nt) acc[z][mt][nt] = (v4f){0.f, 0.f, 0.f, 0.f};

  // fp32 source bases (pre-swizzled column chunk, same algebra as bf16 path)
  const float* axp = x + (size_t)(m0 + wv * 32 + srow) * DM + swz * 8;
  const float* wp0 = Wq + (size_t)(n0 + wv * 16 + srow) * DM + swz * 8;
  const float* wp1 = Wk + (size_t)(n0 + wv * 16 + srow) * DM + swz * 8;
  const float* wp2 = Wv + (size_t)(n0 + wv * 16 + srow) * DM + swz * 8;

  float4 ra[4][2];      // A rows in flight (32 elems)
  float4 rw[3][2][2];   // W rows in flight (48 elems)

#define STG_LOAD(k0_) do {                                                    \
    _Pragma("unroll")                                                         \
    for (int i_ = 0; i_ < 4; ++i_) {                                          \
      ra[i_][0] = *(const float4*)(axp + (size_t)i_ * 8 * DM + (k0_));        \
      ra[i_][1] = *(const float4*)(axp + (size_t)i_ * 8 * DM + (k0_) + 4);    \
    }                                                                         \
    _Pragma("unroll")                                                         \
    for (int i_ = 0; i_ < 2; ++i_) {                                          \
      rw[0][i_][0] = *(const float4*)(wp0 + (size_t)i_ * 8 * DM + (k0_));     \
      rw[0][i_][1] = *(const float4*)(wp0 + (size_t)i_ * 8 * DM + (k0_) + 4); \
      rw[1][i_][0] = *(const float4*)(wp1 + (size_t)i_ * 8 * DM + (k0_));     \
      rw[1][i_][1] = *(const float4*)(wp1 + (size_t)i_ * 8 * DM + (k0_) + 4); \
      rw[2][i_][0] = *(const float4*)(wp2 + (size_t)i_ * 8 * DM + (k0_));     \
      rw[2][i_][1] = *(const float4*)(wp2 + (size_t)i_ * 8 * DM + (k0_) + 4); \
    }                                                                         \
  } while (0)

#define STG_WRITE(buf_) do {                                                  \
    unsigned short* s_ = smem[buf_];                                          \
    _Pragma("unroll")                                                         \
    for (int i_ = 0; i_ < 4; ++i_)                                            \
      *(v8s*)&s_[(wv * 32 + i_ * 8 + srow) * 64 + sslot * 8] =                \
          pack8f(ra[i_][0], ra[i_][1]);                                       \
    _Pragma("unroll")                                                         \
    for (int z_ = 0; z_ < 3; ++z_)                                            \
      _Pragma("unroll")                                                       \
      for (int i_ = 0; i_ < 2; ++i_)                                          \
        *(v8s*)&s_[8192 + z_ * 4096 + (wv * 16 + i_ * 8 + srow) * 64 + sslot * 8] = \
            pack8f(rw[z_][i_][0], rw[z_][i_][1]);                             \
  } while (0)

  STG_LOAD(0);
  STG_WRITE(0);
  __syncthreads();   // buf0 visible to all waves

  int cur = 0;
  for (int k0 = 0; k0 < DM; k0 += 64) {
    if (k0 + 64 < DM) STG_LOAD(k0 + 64);   // fp32 loads fly under compute

    const unsigned short* As = smem[cur];
    const unsigned short* Ws = smem[cur] + 8192;
#pragma unroll
    for (int kc = 0; kc < 2; ++kc) {
      const int aslot = ((kc << 2) | lq) ^ (lrow & 7);
      v8s af[4];
#pragma unroll
      for (int mt = 0; mt < 4; ++mt)
        af[mt] = *(const v8s*)&As[(wm * 64 + mt * 16 + lrow) * 64 + aslot * 8];
#pragma unroll
      for (int z = 0; z < 3; ++z) {
        const unsigned short* Bz = Ws + z * 4096;
        v8s bf[2];
#pragma unroll
        for (int nt = 0; nt < 2; ++nt)
          bf[nt] = *(const v8s*)&Bz[(wn * 32 + nt * 16 + lrow) * 64 + aslot * 8];
#pragma unroll
        for (int mt = 0; mt < 4; ++mt)
#pragma unroll
          for (int nt = 0; nt < 2; ++nt)
            acc[z][mt][nt] = __builtin_amdgcn_mfma_f32_16x16x32_bf16(
                af[mt], bf[nt], acc[z][mt][nt], 0, 0, 0);
      }
    }

    if (k0 + 64 < DM) {
      STG_WRITE(cur ^ 1);   // pack+write next chunk (loads landed during MFMA)
      __syncthreads();      // next buf visible; all waves done reading cur
      cur ^= 1;
    }
  }
#undef STG_LOAD
#undef STG_WRITE

  // Q and K: direct row-major stores
#pragma unroll
  for (int z = 0; z < 2; ++z) {
    unsigned short* Y = z ? Kw : Qw;
#pragma unroll
    for (int mt = 0; mt < 4; ++mt)
#pragma unroll
      for (int nt = 0; nt < 2; ++nt)
#pragma unroll
        for (int r = 0; r < 4; ++r) {
          int row = m0 + wm * 64 + mt * 16 + lq * 4 + r;
          int col = n0 + wn * 32 + nt * 16 + lrow;
          unsigned int p = rne2(acc[z][mt][nt][r], 0.f);   // low16 = value
          Y[(size_t)row * DM + col] = (unsigned short)p;
        }
  }

  // V: stage C-tile [128 t][64 d] swizzled in LDS buffer 0, then b128
  // permuted panel.
  __syncthreads();   // K-loop LDS reads fully done
  {
    unsigned short* stg = smem[0];
#pragma unroll
    for (int mt = 0; mt < 4; ++mt)
#pragma unroll
      for (int nt = 0; nt < 2; ++nt)
#pragma unroll
        for (int r = 0; r < 4; ++r) {
          int trow = wm * 64 + mt * 16 + lq * 4 + r;     // 0..127 (token)
          int col  = wn * 32 + nt * 16 + lrow;           // 0..63  (d)
          int slot = (col >> 3) ^ (trow & 7);
          stg[trow * 64 + slot * 8 + (col & 7)] =
              (unsigned short)rne2(acc[2][mt][nt][r], 0.f);
        }
    __syncthreads();
    {
      const int d = tid & 63;
      const int quarter = tid >> 6;        // 32-key group
      const int bb = m0 >> 11;
      const int tblk = (m0 & 2047) >> 7;
      const int h = n0 >> 6;
      const int bh = bb * 16 + h;
      unsigned short* dst = Vtw + (((size_t)bh * 16 + tblk) * 64 + d) * 128;
      const int ch = d >> 3, e7 = d & 7;
#pragma unroll
      for (int jj = 0; jj < 4; ++jj) {
        unsigned short vals[8];
#pragma unroll
        for (int e = 0; e < 8; ++e) {
          int st = quarter * 32 + (e >> 2) * 16 + jj * 4 + (e & 3);  // key
          vals[e] = stg[st * 64 + (ch ^ (st & 7)) * 8 + e7];
        }
        *(v8s*)(dst + (quarter * 4 + jj) * 8) = *(const v8s*)vals;
      }
    }
  }
}

// ---------------------------------------------------------------------------
// Output projection v3: AO (bf16) via gload16 as before; Wo read as fp32
// directly (reg-staged RNE pack -> ds_write), eliminating its conversion.
// Tile 64M x 128N, grid (64,8) = 512 = 2/CU, structure otherwise R8-proven.
// ---------------------------------------------------------------------------
__global__ __launch_bounds__(256) void oproj_gemm3(
    const unsigned short* __restrict__ AO,
    const float* __restrict__ Wo,
    float* __restrict__ Y)
{
  __shared__ unsigned short smem[12288];   // 24KB
  unsigned short* As = smem;               // [64][64]
  unsigned short* Bs = smem + 4096;        // [128][64]

  const int tid  = threadIdx.x;
  const int wv   = tid >> 6, l = tid & 63;
  const int lrow = l & 15, lq = l >> 4;
  const int wm = wv >> 1;
  const int wn = wv & 1;
  const int srow = l >> 3, sslot = l & 7;
  const int swz  = sslot ^ (srow & 7);
  const int m0 = blockIdx.x * 64, n0 = blockIdx.y * 128;

  v4f acc[2][4];
#pragma unroll
  for (int mt = 0; mt < 2; ++mt)
#pragma unroll
    for (int nt = 0; nt < 4; ++nt) acc[mt][nt] = (v4f){0.f, 0.f, 0.f, 0.f};

  const size_t aBase = (size_t)(m0 + wv * 16 + srow) * DM + swz * 8;
  const float* wop = Wo + (size_t)(n0 + wv * 32 + srow) * DM + swz * 8;

  for (int k0 = 0; k0 < DM; k0 += 64) {
    __syncthreads();
    // Wo fp32 -> regs
    float4 rb[4][2];
#pragma unroll
    for (int i = 0; i < 4; ++i) {
      rb[i][0] = *(const float4*)(wop + (size_t)i * 8 * DM + k0);
      rb[i][1] = *(const float4*)(wop + (size_t)i * 8 * DM + k0 + 4);
    }
    // AO bf16 -> LDS (async)
#pragma unroll
    for (int i = 0; i < 2; ++i)
      gload16(AO + aBase + (size_t)i * 8 * DM + k0, As + (wv * 16 + i * 8) * 64);
    // pack Wo -> LDS
#pragma unroll
    for (int i = 0; i < 4; ++i)
      *(v8s*)&Bs[(wv * 32 + i * 8 + srow) * 64 + sslot * 8] =
          pack8f(rb[i][0], rb[i][1]);
    __syncthreads();
#pragma unroll
    for (int kc = 0; kc < 2; ++kc) {
      const int aslot = ((kc << 2) | lq) ^ (lrow & 7);
      v8s af[2], bf[4];
#pragma unroll
      for (int mt = 0; mt < 2; ++mt)
        af[mt] = *(const v8s*)&As[(wm * 32 + mt * 16 + lrow) * 64 + aslot * 8];
#pragma unroll
      for (int nt = 0; nt < 4; ++nt)
        bf[nt] = *(const v8s*)&Bs[(wn * 64 + nt * 16 + lrow) * 64 + aslot * 8];
#pragma unroll
      for (int mt = 0; mt < 2; ++mt)
#pragma unroll
        for (int nt = 0; nt < 4; ++nt)
          acc[mt][nt] = __builtin_amdgcn_mfma_f32_16x16x32_bf16(
              af[mt], bf[nt], acc[mt][nt], 0, 0, 0);
    }
  }
#pragma unroll
  for (int mt = 0; mt < 2; ++mt)
#pragma unroll
    for (int nt = 0; nt < 4; ++nt)
#pragma unroll
      for (int r = 0; r < 4; ++r) {
        int row = m0 + wm * 32 + mt * 16 + lq * 4 + r;
        int col = n0 + wn * 64 + nt * 16 + lrow;
        Y[(size_t)row * DM + col] = acc[mt][nt][r];
      }
}

// ---------------------------------------------------------------------------
// Flash attention v12 (R6-verified): 32KB single-buffered, 4 blocks/CU,
// grid 1024 LPT, no setprio.  Unchanged.
// ---------------------------------------------------------------------------
__global__ __launch_bounds__(256) void attn12(
    const unsigned short* __restrict__ Q,
    const unsigned short* __restrict__ K,
    const unsigned short* __restrict__ Vt,
    unsigned short* __restrict__ O)
{
  __shared__ unsigned short Ks[128 * 64];   // [key][d chunk swz]   16KB
  __shared__ unsigned short Vts[64 * 128];  // [d][key-perm chunk]  16KB

  const int tid  = threadIdx.x;
  const int wave = tid >> 6;
  const int lane = tid & 63;
  const int lrow = lane & 15;
  const int lq   = lane >> 4;
  const int gid  = blockIdx.x;
  const int qt   = 31 - (gid >> 5);   // LPT: longest first
  const int bh   = gid & 31;
  const int b = bh >> 4, h = bh & 15;

  // ones bf16 A-operand for the row-sum mfma
  union { v8s s; unsigned int u[4]; } ones;
  ones.u[0] = 0x3F803F80u; ones.u[1] = 0x3F803F80u;
  ones.u[2] = 0x3F803F80u; ones.u[3] = 0x3F803F80u;

  // Q fragment = B-operand of S^T mfma: n=q=lrow, k=d=lq*8+j
  const int qrow = qt * 64 + wave * 16 + lrow;
  const unsigned short* qp = Q + ((size_t)(b * T_SEQ + qrow)) * DM + h * 64;
  v8s qf0 = *(const v8s*)(qp + lq * 8);
  v8s qf1 = *(const v8s*)(qp + 32 + lq * 8);

  v4f oacc[4];
#pragma unroll
  for (int dt = 0; dt < 4; ++dt) oacc[dt] = (v4f){0.f, 0.f, 0.f, 0.f};
  v4f sacc = {0.f, 0.f, 0.f, 0.f};

  const int n128 = (qt >> 1) + 1;   // exact # of 128-key tiles (covers qmax)

  // K staging addresses (pre-swizzled global source, linear LDS dest)
  const int kchunk = (lane & 7) ^ ((lane >> 3) & 7);
  const unsigned short* kg =
      K + ((size_t)(b * T_SEQ) + wave * 8 + (lane >> 3)) * DM + h * 64 + kchunk * 8;
  unsigned short* kdst = Ks + (wave * 8) * 64;
  // V staging addresses
  const int vd = wave * 4 + (lane >> 4);
  const int vslot = lane & 15;
  const int vchunk = (vslot & 8) | ((vslot & 7) ^ (vd & 7));
  const unsigned short* vg =
      Vt + ((size_t)bh * 1024 + vd) * 128 + vchunk * 8;
  unsigned short* vdst = Vts + (wave * 4) * 128;

  const int slot0 = lq ^ (lrow & 7);
  const int slot1 = (4 + lq) ^ (lrow & 7);

  for (int tt = 0; tt < n128; ++tt) {
    __syncthreads();   // previous tile's LDS reads complete (cheap at tt=0)
    // stage this 128-key tile (K: 4 gload16, V: 4 gload16 per thread)
#pragma unroll
    for (int i = 0; i < 4; ++i)
      gload16(kg + ((size_t)tt * 128 + i * 32) * DM, kdst + i * 32 * 64);
#pragma unroll
    for (int i = 0; i < 4; ++i)
      gload16(vg + (size_t)tt * 8192 + i * 2048, vdst + i * 16 * 128);
    __syncthreads();   // vmcnt(0) drain: panels ready

    const int kb = tt * 128;

    // S^T = K Q^T : A = K frag (m=key, k=d), B = Q frag
    v4f s[8];
#pragma unroll
    for (int nt = 0; nt < 8; ++nt) {
      v4f a = {0.f, 0.f, 0.f, 0.f};
      v8s k0 = *(const v8s*)&Ks[(nt * 16 + lrow) * 64 + slot0 * 8];
      a = __builtin_amdgcn_mfma_f32_16x16x32_bf16(k0, qf0, a, 0, 0, 0);
      v8s k1 = *(const v8s*)&Ks[(nt * 16 + lrow) * 64 + slot1 * 8];
      a = __builtin_amdgcn_mfma_f32_16x16x32_bf16(k1, qf1, a, 0, 0, 0);
      s[nt] = a;
    }

    // p = exp2(s*0.125*log2e - 16*log2e); mask only when tile crosses diag
    const bool needmask = (kb + 127 > qt * 64 + wave * 16);
    if (needmask) {
#pragma unroll
      for (int nt = 0; nt < 8; ++nt)
#pragma unroll
        for (int r = 0; r < 4; ++r) {
          float p = fast_exp2(fmaf(s[nt][r], 0.18033688f, -23.0831206f));
          if (kb + nt * 16 + lq * 4 + r > qt * 64 + wave * 16 + lrow) p = 0.f;
          s[nt][r] = p;
        }
    } else {
#pragma unroll
      for (int nt = 0; nt < 8; ++nt)
#pragma unroll
        for (int r = 0; r < 4; ++r)
          s[nt][r] = fast_exp2(fmaf(s[nt][r], 0.18033688f, -23.0831206f));
    }

    // P^T stays in registers: pack into K=32 B-operands
    v8s pf[4];
#pragma unroll
    for (int kp = 0; kp < 4; ++kp) pf[kp] = pack8bf(s[2 * kp], s[2 * kp + 1]);

    // O^T += V^T P ; row-sums += ones^T P
#pragma unroll
    for (int kp = 0; kp < 4; ++kp) {
      sacc = __builtin_amdgcn_mfma_f32_16x16x32_bf16(ones.s, pf[kp], sacc, 0, 0, 0);
#pragma unroll
      for (int dt = 0; dt < 4; ++dt) {
        int ch = kp * 4 + lq;
        int slot = (ch & 8) | ((ch & 7) ^ (lrow & 7));
        v8s vv = *(const v8s*)&Vts[(dt * 16 + lrow) * 128 + slot * 8];
        oacc[dt] = __builtin_amdgcn_mfma_f32_16x16x32_bf16(
            vv, pf[kp], oacc[dt], 0, 0, 0);
      }
    }
  }

  // every lane already holds its q's key-sum (all sacc rows identical)
  const float rinv = 1.0f / sacc[0];

  // O^T C-layout: q = lrow, d = dt*16 + lq*4 + r -> b64 packed stores
  const int token = qt * 64 + wave * 16 + lrow;
  unsigned short* op = O + ((size_t)(b * T_SEQ + token)) * DM + h * 64;
#pragma unroll
  for (int dt = 0; dt < 4; ++dt) {
    union { v4s s; unsigned int u[2]; } o;
    o.u[0] = pk2(oacc[dt][0] * rinv, oacc[dt][1] * rinv);
    o.u[1] = pk2(oacc[dt][2] * rinv, oacc[dt][3] * rinv);
    *(v4s*)(op + dt * 16 + lq * 4) = o.s;
  }
}

// ---------------------------------------------------------------------------
extern "C" void kernel_launch(void* const* d_in, const int* in_sizes, int n_in,
                              void* d_out, int out_size, void* d_ws, size_t ws_size,
                              hipStream_t stream) {
  const float* x  = (const float*)d_in[0];
  const float* Wq = (const float*)d_in[1];
  const float* Wk = (const float*)d_in[2];
  const float* Wv = (const float*)d_in[3];
  const float* Wo = (const float*)d_in[4];
  float* out = (float*)d_out;

  unsigned short* Qw  = (unsigned short*)d_ws;
  unsigned short* Kw  = Qw + (size_t)MTOT * DM;
  unsigned short* Vtw = Kw + (size_t)MTOT * DM;
  unsigned short* AO  = Vtw + (size_t)MTOT * DM;

  qkv_fused5<<<dim3(32, 16), 256, 0, stream>>>(x, Wq, Wk, Wv, Qw, Kw, Vtw);
  attn12<<<1024, 256, 0, stream>>>(Qw, Kw, Vtw, AO);
  oproj_gemm3<<<dim3(64, 8), 256, 0, stream>>>(AO, Wo, out);
}